// Round 6
// baseline (442.889 us; speedup 1.0000x reference)
//
#include <hip/hip_runtime.h>
#include <cmath>

// EstimatorQNNGen275: conv+sigmoid+mean -> 1-dim attention -> 4-layer tanh MLP
// (3x 512x4096x4096 GEMMs via fp16 MFMA, split-K, m97-style global_load_lds
// pipeline) -> pairwise-fidelity graph.
//
// R6 = R5 resubmitted (R5 bench died with "container failed twice" -- infra
// flake by all evidence; kernel audit found no deadlock/OOB path).
// R5: GEMM staging rebuilt on the proven m97 pattern: global_load_lds(16B)
// direct-to-LDS DMA (no VGPR round-trip, no cvt on the load path, no
// ds_writes), A as producer-written fp16, W as fp32-in-LDS with cvt at
// fragment read (same RNE casts -> bit-identical numerics). Swizzle done as
// pre-swizzled GLOBAL source + matching XOR on ds_read (both-sides rule).
// One vmcnt(0)+raw-barrier per K-iteration, stage-after-barrier (WAR-safe).
// D-zeroing folded into conv (memset dispatch removed).
//
// ws layout (bytes):
//   [0,2048)     c_buf (512 f32)
//   [4096,4736)  D     (10 dot accumulators, line-padded stride 16 f32)
//   [8192,...)   act1,act2,act3 (f32 8MB each) ; a1h,a2h,a3h (fp16 4MB each,
//                z=8 path) ; part (Z x 8MB split-K partials)

#define NEL (512 * 4096)

typedef float  floatx4 __attribute__((ext_vector_type(4)));
typedef _Float16 halfx8 __attribute__((ext_vector_type(8)));
typedef _Float16 halfx4 __attribute__((ext_vector_type(4)));

__device__ __forceinline__ void gload_lds16(const void* g, void* l) {
  __builtin_amdgcn_global_load_lds(
      (const __attribute__((address_space(1))) void*)g,
      (__attribute__((address_space(3))) void*)l, 16, 0, 0);
}

// ---------------- conv + sigmoid + mean (float4) + D zeroing ----------------
__global__ __launch_bounds__(256) void conv_mean_kernel(
    const float* __restrict__ x, const float* __restrict__ cw,
    const float* __restrict__ cb, float* __restrict__ c_out,
    float* __restrict__ D)
{
  __shared__ float sbuf[4];
  const int b = blockIdx.x;
  if (b == 0 && threadIdx.x < 160) D[threadIdx.x] = 0.f;
  const float w00 = cw[0], w01 = cw[1], w10 = cw[2], w11 = cw[3];
  const float bias = cb[0];
  const float* xb = x + (size_t)b * 128 * 128;
  float acc = 0.f;
  for (int t = threadIdx.x; t < 127 * 32; t += 256) {
    const int i  = t >> 5;
    const int j0 = (t & 31) << 2;
    const float* pr0 = xb + i * 128 + j0;
    const float* pr1 = pr0 + 128;
    const float4 a4 = *reinterpret_cast<const float4*>(pr0);
    const float  a5 = pr0[4];
    const float4 b4 = *reinterpret_cast<const float4*>(pr1);
    const float  b5 = pr1[4];
    const float a[5] = {a4.x, a4.y, a4.z, a4.w, a5};
    const float bb[5] = {b4.x, b4.y, b4.z, b4.w, b5};
    #pragma unroll
    for (int m = 0; m < 4; ++m) {
      if (j0 + m < 127) {
        float v = w00 * a[m] + w01 * a[m + 1] + w10 * bb[m] + w11 * bb[m + 1] + bias;
        acc += 1.0f / (1.0f + __expf(-v));
      }
    }
  }
  #pragma unroll
  for (int off = 32; off > 0; off >>= 1) acc += __shfl_down(acc, off, 64);
  const int lane = threadIdx.x & 63, wv = threadIdx.x >> 6;
  if (lane == 0) sbuf[wv] = acc;
  __syncthreads();
  if (threadIdx.x == 0)
    c_out[b] = (sbuf[0] + sbuf[1] + sbuf[2] + sbuf[3]) * (1.0f / 16129.0f);
}

// -------- attention (wave 0, exact replica) + layer 1 fused (f32 + fp16) ----
__global__ __launch_bounds__(256) void attn_layer1_kernel(
    const float* __restrict__ c, const float* __restrict__ rot,
    const float* __restrict__ ent, const float* __restrict__ W1,
    const float* __restrict__ b1, float* __restrict__ act1,
    _Float16* __restrict__ a1h)
{
  __shared__ float sattn;
  const int i = blockIdx.x;
  if (threadIdx.x < 64) {
    const int lane = threadIdx.x;
    const float t = rot[0] * ent[0] * c[i];
    float vals[8], cj[8];
    float mx = -1e30f;
    #pragma unroll
    for (int u = 0; u < 8; ++u) {
      float cv = c[lane + u * 64];
      cj[u] = cv;
      vals[u] = t * cv;
      mx = fmaxf(mx, vals[u]);
    }
    #pragma unroll
    for (int off = 32; off > 0; off >>= 1) mx = fmaxf(mx, __shfl_down(mx, off, 64));
    mx = __shfl(mx, 0, 64);
    float se = 0.f, sw = 0.f;
    #pragma unroll
    for (int u = 0; u < 8; ++u) {
      float e = __expf(vals[u] - mx);
      se += e;
      sw += e * cj[u];
    }
    #pragma unroll
    for (int off = 32; off > 0; off >>= 1) {
      se += __shfl_down(se, off, 64);
      sw += __shfl_down(sw, off, 64);
    }
    if (lane == 0) sattn = sw / se;
  }
  __syncthreads();
  const float av = sattn;
  #pragma unroll
  for (int k = 0; k < 16; ++k) {
    const int o = k * 256 + threadIdx.x;
    const float v = tanhf(av * W1[o] + b1[o]);
    act1[(size_t)i * 4096 + o] = v;
    a1h[(size_t)i * 4096 + o] = (_Float16)v;
  }
}

// ---------------- fp16-MFMA GEMM: m97-style global_load_lds pipeline --------
// A16: 512 x 4096 fp16 row-major (producer-converted, same RNE cast as the
// old staged version). W: 4096 x 4096 fp32 row-major (N x K), kept fp32 in
// LDS and converted at fragment read (RNE) -> MFMA inputs bit-identical.
// 128x128 tile, BK=32, 256 thr = 4 waves (2x2), wave = 64x64 = 4x4 mfma.
// LDS per buf: A [128][32] fp16 (8KB) + W [128][32] fp32 (16KB); 2 bufs=48KB.
// Swizzle (both-sides): A unit' = u ^ ((row>>1)&3); W unit' = u ^ (row&7).
// Applied by pre-swizzling the per-lane GLOBAL source (LDS dest stays linear
// as global_load_lds requires) and XOR-ing the same pattern on ds_read.
// Loop: vmcnt(0) [own DMAs done] -> s_barrier [all portions done, prior
// readers of the other buf finished] -> stage next tile -> ds_read+cvt+MFMA.
__global__ __launch_bounds__(256, 3) void gemm_kernel(
    const _Float16* __restrict__ A16, const float* __restrict__ W,
    float* __restrict__ part)
{
  __shared__ _Float16 As[2][128][32];   // 16 KB
  __shared__ float    Wsb[2][128][32];  // 32 KB
  const int K = 4096, N = 4096;
  const int tid  = threadIdx.x;
  const int lane = tid & 63;
  const int wave = tid >> 6;
  const int wm = (wave >> 1) * 64;
  const int wn = (wave & 1) * 64;
  const int q  = lane >> 4;
  const int ml = lane & 15;
  const int tileM = blockIdx.y * 128;
  const int tileN = blockIdx.x * 128;
  const int Kslice = K / gridDim.z;
  const int kbeg = blockIdx.z * Kslice;
  const int kend = kbeg + Kslice;
  float* Cb = part + (size_t)blockIdx.z * NEL;

  floatx4 acc[4][4] = {};

  // staging maps (bijections onto the tile; source pre-swizzled)
  const _Float16* asrc[2];  char* adst[2];
  #pragma unroll
  for (int t = 0; t < 2; ++t) {
    const int off = wave * 2048 + t * 1024 + lane * 16;  // byte pos in A buf
    const int r = off >> 6;                              // row (64 B rows)
    const int u = ((off >> 4) & 3) ^ ((r >> 1) & 3);     // logical 16B unit
    asrc[t] = A16 + (size_t)(tileM + r) * K + u * 8;
    adst[t] = (char*)&As[0][0][0] + wave * 2048 + t * 1024;  // wave-uniform
  }
  const float* wsrc[4];  char* wdst[4];
  #pragma unroll
  for (int t = 0; t < 4; ++t) {
    const int off = wave * 4096 + t * 1024 + lane * 16;  // byte pos in W buf
    const int r = off >> 7;                              // row (128 B rows)
    const int u = ((off >> 4) & 7) ^ (r & 7);            // logical 16B unit
    wsrc[t] = W + (size_t)(tileN + r) * K + u * 4;
    wdst[t] = (char*)&Wsb[0][0][0] + wave * 4096 + t * 1024;
  }

  auto stage = [&](int buf, int k0) {
    #pragma unroll
    for (int t = 0; t < 2; ++t)
      gload_lds16(asrc[t] + k0, adst[t] + buf * 8192);
    #pragma unroll
    for (int t = 0; t < 4; ++t)
      gload_lds16(wsrc[t] + k0, wdst[t] + buf * 16384);
  };

  stage(0, kbeg);
  int cur = 0;

  for (int k0 = kbeg; k0 < kend; k0 += 32) {
    // own DMA portion of buf[cur] complete, then block-wide publish.
    asm volatile("s_waitcnt vmcnt(0)" ::: "memory");
    __builtin_amdgcn_s_barrier();

    if (k0 + 32 < kend) stage(cur ^ 1, k0 + 32);  // in flight through MFMA

    halfx8 af[4], bf[4];
    #pragma unroll
    for (int i = 0; i < 4; ++i) {
      const int r = wm + i * 16 + ml;
      af[i] = *reinterpret_cast<const halfx8*>(
          &As[cur][r][(q ^ ((r >> 1) & 3)) << 3]);
    }
    #pragma unroll
    for (int j = 0; j < 4; ++j) {
      const int r = wn + j * 16 + ml;
      const int s = r & 7;
      const float4 w0 = *reinterpret_cast<const float4*>(
          &Wsb[cur][r][((2 * q) ^ s) << 2]);
      const float4 w1 = *reinterpret_cast<const float4*>(
          &Wsb[cur][r][((2 * q + 1) ^ s) << 2]);
      bf[j] = halfx8{ (_Float16)w0.x, (_Float16)w0.y,
                      (_Float16)w0.z, (_Float16)w0.w,
                      (_Float16)w1.x, (_Float16)w1.y,
                      (_Float16)w1.z, (_Float16)w1.w };
    }

    #pragma unroll
    for (int i = 0; i < 4; ++i)
      #pragma unroll
      for (int j = 0; j < 4; ++j)
        acc[i][j] = __builtin_amdgcn_mfma_f32_16x16x32_f16(af[i], bf[j], acc[i][j], 0, 0, 0);

    cur ^= 1;
  }

  // C/D layout: col=lane&15, row=(lane>>4)*4+reg
  #pragma unroll
  for (int i = 0; i < 4; ++i) {
    const int row0 = tileM + wm + i * 16 + q * 4;
    #pragma unroll
    for (int j = 0; j < 4; ++j) {
      const int col = tileN + wn + j * 16 + ml;
      #pragma unroll
      for (int r = 0; r < 4; ++r)
        Cb[(size_t)(row0 + r) * N + col] = acc[i][j][r];
    }
  }
}

// -------- split-K combine: sum S slices + bias + tanh (+ fp16 copy) --------
template<int S, bool H>
__global__ __launch_bounds__(256) void combine_tanh_kernel(
    const float* __restrict__ part, const float* __restrict__ bias,
    float* __restrict__ outp, _Float16* __restrict__ houtp)
{
  const int i4 = blockIdx.x * 256 + threadIdx.x;  // < NEL/4
  const floatx4* p4 = (const floatx4*)part;
  floatx4 s = p4[i4];
  #pragma unroll
  for (int z = 1; z < S; ++z) s += p4[(size_t)z * (NEL / 4) + i4];
  const floatx4 bv = ((const floatx4*)bias)[i4 & 1023];
  floatx4 o;
  #pragma unroll
  for (int r = 0; r < 4; ++r) o[r] = tanhf(s[r] + bv[r]);
  ((floatx4*)outp)[i4] = o;
  if (H) {
    halfx4 h = { (_Float16)o[0], (_Float16)o[1], (_Float16)o[2], (_Float16)o[3] };
    ((halfx4*)houtp)[i4] = h;
  }
}

// ---------------- fid pairwise dots (low-contention) ----------------
__global__ __launch_bounds__(256) void fid_dots_kernel(
    const float* __restrict__ a1, const float* __restrict__ a2,
    const float* __restrict__ a3, const float* __restrict__ a4,
    float* __restrict__ D)
{
  __shared__ float sred[4][10];
  float s[10] = {0, 0, 0, 0, 0, 0, 0, 0, 0, 0};
  const int n4 = NEL / 4;
  const int stride = gridDim.x * blockDim.x;
  const floatx4* p1 = (const floatx4*)a1;
  const floatx4* p2 = (const floatx4*)a2;
  const floatx4* p3 = (const floatx4*)a3;
  const floatx4* p4 = (const floatx4*)a4;
  for (int i = blockIdx.x * 256 + threadIdx.x; i < n4; i += stride) {
    floatx4 v1 = p1[i], v2 = p2[i], v3 = p3[i], v4 = p4[i];
    #pragma unroll
    for (int r = 0; r < 4; ++r) {
      s[0] += v1[r] * v1[r]; s[1] += v1[r] * v2[r]; s[2] += v1[r] * v3[r];
      s[3] += v1[r] * v4[r]; s[4] += v2[r] * v2[r]; s[5] += v2[r] * v3[r];
      s[6] += v2[r] * v4[r]; s[7] += v3[r] * v3[r]; s[8] += v3[r] * v4[r];
      s[9] += v4[r] * v4[r];
    }
  }
  const int lane = threadIdx.x & 63, wv = threadIdx.x >> 6;
  #pragma unroll
  for (int p = 0; p < 10; ++p) {
    float v = s[p];
    #pragma unroll
    for (int off = 32; off > 0; off >>= 1) v += __shfl_down(v, off, 64);
    if (lane == 0) sred[wv][p] = v;
  }
  __syncthreads();
  if (threadIdx.x < 10) {
    float v = sred[0][threadIdx.x] + sred[1][threadIdx.x] +
              sred[2][threadIdx.x] + sred[3][threadIdx.x];
    atomicAdd(&D[threadIdx.x * 16], v);
  }
}

// ---------------- finalize graph weights ----------------
__global__ void finalize_kernel(const float* __restrict__ D, float* __restrict__ wout)
{
  const int i = threadIdx.x;
  if (i >= 16) return;
  const int p = i >> 2, qq = i & 3;
  const int a = p < qq ? p : qq;
  const int b = p < qq ? qq : p;
  const int base[4] = {0, 4, 7, 9};
  const float dpq = D[(base[a] + (b - a)) * 16];
  const float npv = sqrtf(D[base[p] * 16]) + 1e-12f;
  const float nqv = sqrtf(D[base[qq] * 16]) + 1e-12f;
  const float ch = dpq / (npv * nqv);
  const float fid = ch * ch;
  wout[i] = (fid >= 0.8f && p != qq) ? 1.0f : 0.0f;
}

extern "C" void kernel_launch(void* const* d_in, const int* in_sizes, int n_in,
                              void* d_out, int out_size, void* d_ws, size_t ws_size,
                              hipStream_t stream)
{
  const float* x   = (const float*)d_in[0];
  const float* cw  = (const float*)d_in[1];
  const float* cb  = (const float*)d_in[2];
  const float* rot = (const float*)d_in[3];
  const float* ent = (const float*)d_in[4];
  const float* W1  = (const float*)d_in[5];
  const float* b1  = (const float*)d_in[6];
  const float* W2  = (const float*)d_in[7];
  const float* b2  = (const float*)d_in[8];
  const float* W3  = (const float*)d_in[9];
  const float* b3  = (const float*)d_in[10];
  const float* W4  = (const float*)d_in[11];
  const float* b4  = (const float*)d_in[12];
  float* out = (float*)d_out;

  char*  ws    = (char*)d_ws;
  float* c_buf = (float*)(ws + 0);
  float* D     = (float*)(ws + 4096);
  float* act1  = (float*)(ws + 8192);
  float* act2  = act1 + NEL;
  float* act3  = act2 + NEL;
  _Float16* a1h = (_Float16*)(act3 + NEL);
  _Float16* a2h = a1h + NEL;
  _Float16* a3h = a2h + NEL;
  float* part  = (float*)(a3h + NEL);  // Z x NEL fp32 split-K partials
  float* wout  = out + NEL;

  const size_t base_need = 8192 + (size_t)3 * NEL * 4 + (size_t)3 * NEL * 2;
  const bool sk8 = ws_size >= base_need + (size_t)8 * NEL * 4;  // ~101 MB

  conv_mean_kernel<<<512, 256, 0, stream>>>(x, cw, cb, c_buf, D);
  attn_layer1_kernel<<<512, 256, 0, stream>>>(c_buf, rot, ent, W1, b1, act1, a1h);

  const int cgrid = NEL / 4 / 256;
  if (sk8) {
    dim3 g(32, 4, 8);  // 1024 blocks, 3 blocks/CU (48KB LDS)
    gemm_kernel<<<g, 256, 0, stream>>>(a1h, W2, part);
    combine_tanh_kernel<8, true><<<cgrid, 256, 0, stream>>>(part, b2, act2, a2h);
    gemm_kernel<<<g, 256, 0, stream>>>(a2h, W3, part);
    combine_tanh_kernel<8, true><<<cgrid, 256, 0, stream>>>(part, b3, act3, a3h);
    gemm_kernel<<<g, 256, 0, stream>>>(a3h, W4, part);
    combine_tanh_kernel<8, false><<<cgrid, 256, 0, stream>>>(part, b4, out, nullptr);
  } else {
    dim3 g(32, 4, 4);  // 512 blocks; fits the proven 88 MB workspace
    gemm_kernel<<<g, 256, 0, stream>>>(a1h, W2, part);
    combine_tanh_kernel<4, true><<<cgrid, 256, 0, stream>>>(part, b2, act2, a2h);
    gemm_kernel<<<g, 256, 0, stream>>>(a2h, W3, part);
    combine_tanh_kernel<4, true><<<cgrid, 256, 0, stream>>>(part, b3, act3, a3h);
    gemm_kernel<<<g, 256, 0, stream>>>(a3h, W4, part);
    combine_tanh_kernel<4, false><<<cgrid, 256, 0, stream>>>(part, b4, out, nullptr);
  }

  fid_dots_kernel<<<256, 256, 0, stream>>>(act1, act2, act3, out, D);
  finalize_kernel<<<1, 64, 0, stream>>>(D, wout);
}

// Round 7
// 404.059 us; speedup vs baseline: 1.0961x; 1.0961x over previous
//
#include <hip/hip_runtime.h>
#include <cmath>

// EstimatorQNNGen275: conv+sigmoid+mean -> 1-dim attention -> 4-layer tanh MLP
// (3x 512x4096x4096 GEMMs via fp16 MFMA, split-K, dbuf raw-barrier pipeline)
// -> pairwise-fidelity graph.
//
// R7: W pre-converted to fp16 (wconv streaming kernel, identical RNE cast the
// GEMM's store_tile used to apply -> bit-identical MFMA inputs). GEMM is the
// proven R1 structure with BOTH operands fp16: 16B staging loads, 16KB/buf
// LDS tiles, no cvt in the K-loop. Rationale: R1/R2/R4/R6 proved gemm dur is
// invariant to staging mechanism/LDS/swizzle/occupancy; the only un-varied
// axis is W's 64MB fp32 stream, which thrashes per-XCD L2 (8MB working set
// vs 4MB) and serializes on L3 BW. Halving W bytes halves that stream.
// Single Wh buffer reused across the three layers (stream is serial).
//
// ws layout (bytes):
//   [0,2048)     c_buf (512 f32)
//   [4096,4736)  D     (10 dot accumulators, line-padded stride 16 f32)
//   [8192,...)   act1,act2,act3 (f32 8MB each) ; a1h,a2h,a3h (fp16 4MB each)
//                ; wh (fp16 32MB) ; part (Z x 8MB split-K partials)

#define NEL (512 * 4096)

typedef float  floatx4 __attribute__((ext_vector_type(4)));
typedef _Float16 halfx8 __attribute__((ext_vector_type(8)));
typedef _Float16 halfx4 __attribute__((ext_vector_type(4)));

#define BM 128
#define BN 128
#define BK 32
#define LDK 40  // padded leading dim (halfs), R1-proven

// ---------------- conv + sigmoid + mean (float4) + D zeroing ----------------
__global__ __launch_bounds__(256) void conv_mean_kernel(
    const float* __restrict__ x, const float* __restrict__ cw,
    const float* __restrict__ cb, float* __restrict__ c_out,
    float* __restrict__ D)
{
  __shared__ float sbuf[4];
  const int b = blockIdx.x;
  if (b == 0 && threadIdx.x < 160) D[threadIdx.x] = 0.f;
  const float w00 = cw[0], w01 = cw[1], w10 = cw[2], w11 = cw[3];
  const float bias = cb[0];
  const float* xb = x + (size_t)b * 128 * 128;
  float acc = 0.f;
  for (int t = threadIdx.x; t < 127 * 32; t += 256) {
    const int i  = t >> 5;
    const int j0 = (t & 31) << 2;
    const float* pr0 = xb + i * 128 + j0;
    const float* pr1 = pr0 + 128;
    const float4 a4 = *reinterpret_cast<const float4*>(pr0);
    const float  a5 = pr0[4];
    const float4 b4 = *reinterpret_cast<const float4*>(pr1);
    const float  b5 = pr1[4];
    const float a[5] = {a4.x, a4.y, a4.z, a4.w, a5};
    const float bb[5] = {b4.x, b4.y, b4.z, b4.w, b5};
    #pragma unroll
    for (int m = 0; m < 4; ++m) {
      if (j0 + m < 127) {
        float v = w00 * a[m] + w01 * a[m + 1] + w10 * bb[m] + w11 * bb[m + 1] + bias;
        acc += 1.0f / (1.0f + __expf(-v));
      }
    }
  }
  #pragma unroll
  for (int off = 32; off > 0; off >>= 1) acc += __shfl_down(acc, off, 64);
  const int lane = threadIdx.x & 63, wv = threadIdx.x >> 6;
  if (lane == 0) sbuf[wv] = acc;
  __syncthreads();
  if (threadIdx.x == 0)
    c_out[b] = (sbuf[0] + sbuf[1] + sbuf[2] + sbuf[3]) * (1.0f / 16129.0f);
}

// -------- attention (wave 0, exact replica) + layer 1 fused (f32 + fp16) ----
__global__ __launch_bounds__(256) void attn_layer1_kernel(
    const float* __restrict__ c, const float* __restrict__ rot,
    const float* __restrict__ ent, const float* __restrict__ W1,
    const float* __restrict__ b1, float* __restrict__ act1,
    _Float16* __restrict__ a1h)
{
  __shared__ float sattn;
  const int i = blockIdx.x;
  if (threadIdx.x < 64) {
    const int lane = threadIdx.x;
    const float t = rot[0] * ent[0] * c[i];
    float vals[8], cj[8];
    float mx = -1e30f;
    #pragma unroll
    for (int u = 0; u < 8; ++u) {
      float cv = c[lane + u * 64];
      cj[u] = cv;
      vals[u] = t * cv;
      mx = fmaxf(mx, vals[u]);
    }
    #pragma unroll
    for (int off = 32; off > 0; off >>= 1) mx = fmaxf(mx, __shfl_down(mx, off, 64));
    mx = __shfl(mx, 0, 64);
    float se = 0.f, sw = 0.f;
    #pragma unroll
    for (int u = 0; u < 8; ++u) {
      float e = __expf(vals[u] - mx);
      se += e;
      sw += e * cj[u];
    }
    #pragma unroll
    for (int off = 32; off > 0; off >>= 1) {
      se += __shfl_down(se, off, 64);
      sw += __shfl_down(sw, off, 64);
    }
    if (lane == 0) sattn = sw / se;
  }
  __syncthreads();
  const float av = sattn;
  #pragma unroll
  for (int k = 0; k < 16; ++k) {
    const int o = k * 256 + threadIdx.x;
    const float v = tanhf(av * W1[o] + b1[o]);
    act1[(size_t)i * 4096 + o] = v;
    a1h[(size_t)i * 4096 + o] = (_Float16)v;
  }
}

// ---------------- W fp32 -> fp16 streaming conversion (RNE) ----------------
__global__ __launch_bounds__(256) void wconv_kernel(
    const float* __restrict__ w, _Float16* __restrict__ wh)
{
  const int n8 = 4096 * 4096 / 8;          // 2M groups of 8 floats
  const int stride = gridDim.x * 256;
  const float4* w4 = (const float4*)w;
  for (int i = blockIdx.x * 256 + threadIdx.x; i < n8; i += stride) {
    const float4 a = w4[2 * i];
    const float4 b = w4[2 * i + 1];
    halfx8 h = { (_Float16)a.x, (_Float16)a.y, (_Float16)a.z, (_Float16)a.w,
                 (_Float16)b.x, (_Float16)b.y, (_Float16)b.z, (_Float16)b.w };
    ((halfx8*)wh)[i] = h;
  }
}

// ---------------- fp16-MFMA GEMM (R1 structure, both operands fp16) ---------
// A16: 512 x 4096 fp16 row-major. W16: 4096 x 4096 fp16 row-major (N x K).
// 128x128 tile, BK=32, 256 thr = 4 waves (2x2), wave = 64x64 = 4x4 mfma.
// Raw barrier + lgkm-only drain (R1): prefetch global loads stay in flight
// across the barrier; compiler's vmcnt wait lands at store_tile.
__global__ __launch_bounds__(256, 4) void gemm_kernel(
    const _Float16* __restrict__ A16, const _Float16* __restrict__ W16,
    float* __restrict__ part)
{
  __shared__ _Float16 As[2][BM][LDK];
  __shared__ _Float16 Ws[2][BN][LDK];
  const int K = 4096, N = 4096;
  const int tid  = threadIdx.x;
  const int lane = tid & 63;
  const int wave = tid >> 6;
  const int wm = (wave >> 1) * 64;
  const int wn = (wave & 1) * 64;
  const int q  = lane >> 4;
  const int ml = lane & 15;
  const int tileM = blockIdx.y * BM;
  const int tileN = blockIdx.x * BN;
  const int Kslice = K / gridDim.z;
  const int kbeg = blockIdx.z * Kslice;
  const int kend = kbeg + Kslice;
  float* Cb = part + (size_t)blockIdx.z * NEL;

  floatx4 acc[4][4] = {};

  // staging map: thread covers rows r0 and r0+64, cols cc0..cc0+7 (halfx8)
  const int r0  = tid >> 2;
  const int cc0 = (tid & 3) << 3;

  halfx8 pa[2], pw[2];
  auto load_tile = [&](int k0) {
    #pragma unroll
    for (int u = 0; u < 2; ++u) {
      pa[u] = *reinterpret_cast<const halfx8*>(
          A16 + (size_t)(tileM + r0 + u * 64) * K + k0 + cc0);
      pw[u] = *reinterpret_cast<const halfx8*>(
          W16 + (size_t)(tileN + r0 + u * 64) * K + k0 + cc0);
    }
  };
  auto store_tile = [&](int buf) {
    #pragma unroll
    for (int u = 0; u < 2; ++u) {
      *reinterpret_cast<halfx8*>(&As[buf][r0 + u * 64][cc0]) = pa[u];
      *reinterpret_cast<halfx8*>(&Ws[buf][r0 + u * 64][cc0]) = pw[u];
    }
  };

  // prologue: fill buf 0
  load_tile(kbeg);
  store_tile(0);
  int cur = 0;

  for (int k0 = kbeg; k0 < kend; k0 += BK) {
    const bool more = (k0 + BK < kend);
    if (more) load_tile(k0 + BK);   // stays in flight across the raw barrier

    asm volatile("s_waitcnt lgkmcnt(0)" ::: "memory");
    __builtin_amdgcn_s_barrier();

    halfx8 af[4], bf[4];
    #pragma unroll
    for (int i = 0; i < 4; ++i)
      af[i] = *reinterpret_cast<const halfx8*>(&As[cur][wm + i * 16 + ml][q * 8]);
    #pragma unroll
    for (int j = 0; j < 4; ++j)
      bf[j] = *reinterpret_cast<const halfx8*>(&Ws[cur][wn + j * 16 + ml][q * 8]);

    #pragma unroll
    for (int i = 0; i < 4; ++i)
      #pragma unroll
      for (int j = 0; j < 4; ++j)
        acc[i][j] = __builtin_amdgcn_mfma_f32_16x16x32_f16(af[i], bf[j], acc[i][j], 0, 0, 0);

    if (more) store_tile(cur ^ 1);  // compiler's vmcnt wait lands here
    cur ^= 1;
  }

  // C/D layout: col=lane&15, row=(lane>>4)*4+reg
  #pragma unroll
  for (int i = 0; i < 4; ++i) {
    const int row0 = tileM + wm + i * 16 + q * 4;
    #pragma unroll
    for (int j = 0; j < 4; ++j) {
      const int col = tileN + wn + j * 16 + ml;
      #pragma unroll
      for (int r = 0; r < 4; ++r)
        Cb[(size_t)(row0 + r) * N + col] = acc[i][j][r];
    }
  }
}

// -------- split-K combine: sum S slices + bias + tanh (+ fp16 copy) --------
template<int S, bool H>
__global__ __launch_bounds__(256) void combine_tanh_kernel(
    const float* __restrict__ part, const float* __restrict__ bias,
    float* __restrict__ outp, _Float16* __restrict__ houtp)
{
  const int i4 = blockIdx.x * 256 + threadIdx.x;  // < NEL/4
  const floatx4* p4 = (const floatx4*)part;
  floatx4 s = p4[i4];
  #pragma unroll
  for (int z = 1; z < S; ++z) s += p4[(size_t)z * (NEL / 4) + i4];
  const floatx4 bv = ((const floatx4*)bias)[i4 & 1023];
  floatx4 o;
  #pragma unroll
  for (int r = 0; r < 4; ++r) o[r] = tanhf(s[r] + bv[r]);
  ((floatx4*)outp)[i4] = o;
  if (H) {
    halfx4 h = { (_Float16)o[0], (_Float16)o[1], (_Float16)o[2], (_Float16)o[3] };
    ((halfx4*)houtp)[i4] = h;
  }
}

// ---------------- fid pairwise dots (low-contention) ----------------
__global__ __launch_bounds__(256) void fid_dots_kernel(
    const float* __restrict__ a1, const float* __restrict__ a2,
    const float* __restrict__ a3, const float* __restrict__ a4,
    float* __restrict__ D)
{
  __shared__ float sred[4][10];
  float s[10] = {0, 0, 0, 0, 0, 0, 0, 0, 0, 0};
  const int n4 = NEL / 4;
  const int stride = gridDim.x * blockDim.x;
  const floatx4* p1 = (const floatx4*)a1;
  const floatx4* p2 = (const floatx4*)a2;
  const floatx4* p3 = (const floatx4*)a3;
  const floatx4* p4 = (const floatx4*)a4;
  for (int i = blockIdx.x * 256 + threadIdx.x; i < n4; i += stride) {
    floatx4 v1 = p1[i], v2 = p2[i], v3 = p3[i], v4 = p4[i];
    #pragma unroll
    for (int r = 0; r < 4; ++r) {
      s[0] += v1[r] * v1[r]; s[1] += v1[r] * v2[r]; s[2] += v1[r] * v3[r];
      s[3] += v1[r] * v4[r]; s[4] += v2[r] * v2[r]; s[5] += v2[r] * v3[r];
      s[6] += v2[r] * v4[r]; s[7] += v3[r] * v3[r]; s[8] += v3[r] * v4[r];
      s[9] += v4[r] * v4[r];
    }
  }
  const int lane = threadIdx.x & 63, wv = threadIdx.x >> 6;
  #pragma unroll
  for (int p = 0; p < 10; ++p) {
    float v = s[p];
    #pragma unroll
    for (int off = 32; off > 0; off >>= 1) v += __shfl_down(v, off, 64);
    if (lane == 0) sred[wv][p] = v;
  }
  __syncthreads();
  if (threadIdx.x < 10) {
    float v = sred[0][threadIdx.x] + sred[1][threadIdx.x] +
              sred[2][threadIdx.x] + sred[3][threadIdx.x];
    atomicAdd(&D[threadIdx.x * 16], v);
  }
}

// ---------------- finalize graph weights ----------------
__global__ void finalize_kernel(const float* __restrict__ D, float* __restrict__ wout)
{
  const int i = threadIdx.x;
  if (i >= 16) return;
  const int p = i >> 2, qq = i & 3;
  const int a = p < qq ? p : qq;
  const int b = p < qq ? qq : p;
  const int base[4] = {0, 4, 7, 9};
  const float dpq = D[(base[a] + (b - a)) * 16];
  const float npv = sqrtf(D[base[p] * 16]) + 1e-12f;
  const float nqv = sqrtf(D[base[qq] * 16]) + 1e-12f;
  const float ch = dpq / (npv * nqv);
  const float fid = ch * ch;
  wout[i] = (fid >= 0.8f && p != qq) ? 1.0f : 0.0f;
}

extern "C" void kernel_launch(void* const* d_in, const int* in_sizes, int n_in,
                              void* d_out, int out_size, void* d_ws, size_t ws_size,
                              hipStream_t stream)
{
  const float* x   = (const float*)d_in[0];
  const float* cw  = (const float*)d_in[1];
  const float* cb  = (const float*)d_in[2];
  const float* rot = (const float*)d_in[3];
  const float* ent = (const float*)d_in[4];
  const float* W1  = (const float*)d_in[5];
  const float* b1  = (const float*)d_in[6];
  const float* W2  = (const float*)d_in[7];
  const float* b2  = (const float*)d_in[8];
  const float* W3  = (const float*)d_in[9];
  const float* b3  = (const float*)d_in[10];
  const float* W4  = (const float*)d_in[11];
  const float* b4  = (const float*)d_in[12];
  float* out = (float*)d_out;

  char*  ws    = (char*)d_ws;
  float* c_buf = (float*)(ws + 0);
  float* D     = (float*)(ws + 4096);
  float* act1  = (float*)(ws + 8192);
  float* act2  = act1 + NEL;
  float* act3  = act2 + NEL;
  _Float16* a1h = (_Float16*)(act3 + NEL);
  _Float16* a2h = a1h + NEL;
  _Float16* a3h = a2h + NEL;
  _Float16* wh  = a3h + NEL;                       // 4096x4096 fp16 = 32MB
  float* part  = (float*)(wh + (size_t)4096 * 4096);  // Z x NEL fp32 partials
  float* wout  = out + NEL;

  const size_t base_need = 8192 + (size_t)3 * NEL * 4 + (size_t)3 * NEL * 2
                         + (size_t)4096 * 4096 * 2;  // ~68 MB
  const bool sk8 = ws_size >= base_need + (size_t)8 * NEL * 4;  // ~132 MB
  // z=4 fallback needs base_need + 32MB = ~100MB == R6's proven footprint.

  conv_mean_kernel<<<512, 256, 0, stream>>>(x, cw, cb, c_buf, D);
  attn_layer1_kernel<<<512, 256, 0, stream>>>(c_buf, rot, ent, W1, b1, act1, a1h);

  const int cgrid = NEL / 4 / 256;
  if (sk8) {
    dim3 g(32, 4, 8);  // 1024 blocks, 4 blocks/CU (32KB LDS) single generation
    wconv_kernel<<<2048, 256, 0, stream>>>(W2, wh);
    gemm_kernel<<<g, 256, 0, stream>>>(a1h, wh, part);
    combine_tanh_kernel<8, true><<<cgrid, 256, 0, stream>>>(part, b2, act2, a2h);
    wconv_kernel<<<2048, 256, 0, stream>>>(W3, wh);
    gemm_kernel<<<g, 256, 0, stream>>>(a2h, wh, part);
    combine_tanh_kernel<8, true><<<cgrid, 256, 0, stream>>>(part, b3, act3, a3h);
    wconv_kernel<<<2048, 256, 0, stream>>>(W4, wh);
    gemm_kernel<<<g, 256, 0, stream>>>(a3h, wh, part);
    combine_tanh_kernel<8, false><<<cgrid, 256, 0, stream>>>(part, b4, out, nullptr);
  } else {
    dim3 g(32, 4, 4);  // 512 blocks; footprint == R6's proven 100MB
    wconv_kernel<<<2048, 256, 0, stream>>>(W2, wh);
    gemm_kernel<<<g, 256, 0, stream>>>(a1h, wh, part);
    combine_tanh_kernel<4, true><<<cgrid, 256, 0, stream>>>(part, b2, act2, a2h);
    wconv_kernel<<<2048, 256, 0, stream>>>(W3, wh);
    gemm_kernel<<<g, 256, 0, stream>>>(a2h, wh, part);
    combine_tanh_kernel<4, true><<<cgrid, 256, 0, stream>>>(part, b3, act3, a3h);
    wconv_kernel<<<2048, 256, 0, stream>>>(W4, wh);
    gemm_kernel<<<g, 256, 0, stream>>>(a3h, wh, part);
    combine_tanh_kernel<4, false><<<cgrid, 256, 0, stream>>>(part, b4, out, nullptr);
  }

  fid_dots_kernel<<<256, 256, 0, stream>>>(act1, act2, act3, out, D);
  finalize_kernel<<<1, 64, 0, stream>>>(D, wout);
}